// Round 1
// baseline (101.948 us; speedup 1.0000x reference)
//
#include <hip/hip_runtime.h>
#include <math.h>

#define BB 4
#define ND 256
#define NE 512
#define CC 256

// ---------------------------------------------------------------------------
// fast tanh: tanh(x) = (e^{2x}-1)/(e^{2x}+1), clamped so exp never overflows.
// v_exp_f32 + v_rcp_f32, ~1ulp each -> plenty for the 0.175 absmax threshold.
// ---------------------------------------------------------------------------
__device__ __forceinline__ float fast_tanh(float x) {
    float cx = fminf(fmaxf(x, -10.0f), 10.0f);
    float u  = __expf(2.0f * cx);
    return __fdividef(u - 1.0f, u + 1.0f);
}

// ---------------------------------------------------------------------------
// Projection GEMM: Y[r,d] = sum_c X[r,c] * W[d,c]   (torch Linear, y = x W^T)
// rows 0..2047  : X = x_encoder, W = w1, Y = enc_t
// rows 2048..3071: X = x_decoder, W = w2, Y = dec_t
// 64x64 tile per 256-thread block, K-step 16, fp32 vector FMA.
// ---------------------------------------------------------------------------
__global__ __launch_bounds__(256) void proj_kernel(
    const float* __restrict__ xdec, const float* __restrict__ xenc,
    const float* __restrict__ w1,   const float* __restrict__ w2,
    float* __restrict__ enc_t, float* __restrict__ dec_t)
{
    __shared__ float Xs[16][68];   // [k][row], pad 68 -> 2-way max (free)
    __shared__ float Ws[16][68];   // [k][col]

    const int row0 = blockIdx.x * 64;
    const int col0 = blockIdx.y * 64;
    const bool is_enc = (row0 < BB * NE);

    const float* X = is_enc ? xenc : xdec;
    const float* W = is_enc ? w1   : w2;
    float*       Y = is_enc ? enc_t : dec_t;
    const int xrow0 = is_enc ? row0 : (row0 - BB * NE);

    const int tid = threadIdx.x;
    const int lr = tid >> 2;           // 0..63   loader row
    const int lk = (tid & 3) << 2;     // 0,4,8,12 loader k-offset
    const int ty = tid >> 4;           // 0..15   compute row-group
    const int tx = tid & 15;           // 0..15   compute col-group

    float acc[4][4] = {};

    for (int k0 = 0; k0 < CC; k0 += 16) {
        float4 xv = *(const float4*)&X[(xrow0 + lr) * CC + k0 + lk];
        float4 wv = *(const float4*)&W[(col0  + lr) * CC + k0 + lk];
        __syncthreads();
        Xs[lk + 0][lr] = xv.x; Xs[lk + 1][lr] = xv.y;
        Xs[lk + 2][lr] = xv.z; Xs[lk + 3][lr] = xv.w;
        Ws[lk + 0][lr] = wv.x; Ws[lk + 1][lr] = wv.y;
        Ws[lk + 2][lr] = wv.z; Ws[lk + 3][lr] = wv.w;
        __syncthreads();
#pragma unroll
        for (int k = 0; k < 16; ++k) {
            float4 a = *(const float4*)&Xs[k][ty * 4];
            float4 b = *(const float4*)&Ws[k][tx * 4];
            acc[0][0] += a.x * b.x; acc[0][1] += a.x * b.y;
            acc[0][2] += a.x * b.z; acc[0][3] += a.x * b.w;
            acc[1][0] += a.y * b.x; acc[1][1] += a.y * b.y;
            acc[1][2] += a.y * b.z; acc[1][3] += a.y * b.w;
            acc[2][0] += a.z * b.x; acc[2][1] += a.z * b.y;
            acc[2][2] += a.z * b.z; acc[2][3] += a.z * b.w;
            acc[3][0] += a.w * b.x; acc[3][1] += a.w * b.y;
            acc[3][2] += a.w * b.z; acc[3][3] += a.w * b.w;
        }
    }

#pragma unroll
    for (int i = 0; i < 4; ++i) {
        float4 o = make_float4(acc[i][0], acc[i][1], acc[i][2], acc[i][3]);
        *(float4*)&Y[(xrow0 + ty * 4 + i) * CC + col0 + tx * 4] = o;
    }
}

// ---------------------------------------------------------------------------
// Fused tanh-dot + log_softmax.
// One block (256 thr, 4 waves) per (b, n) row. 16-lane subgroups own one e
// each; lane covers 16 c via float4 loads; 4-shuffle subgroup reduction.
// ---------------------------------------------------------------------------
__global__ __launch_bounds__(256) void attn_kernel(
    const float* __restrict__ enc_t, const float* __restrict__ dec_t,
    const float* __restrict__ v, float* __restrict__ out)
{
    __shared__ float dec_s[CC];
    __shared__ float v_s[CC];
    __shared__ float prod[NE];
    __shared__ float red[8];

    const int bn = blockIdx.x;            // 0..1023
    const int b  = bn >> 8;
    const int tid = threadIdx.x;

    dec_s[tid] = dec_t[bn * CC + tid];    // (b*ND + n) * CC == bn * CC
    v_s[tid]   = v[tid];
    __syncthreads();

    const int lane = tid & 63;
    const int w    = tid >> 6;            // wave 0..3
    const int g    = lane >> 4;           // subgroup 0..3
    const int gl   = lane & 15;           // lane-in-subgroup
    const float* encb = enc_t + b * NE * CC;

    for (int e0 = 0; e0 < NE; e0 += 16) {
        const int e = e0 + w * 4 + g;
        const float* er = encb + e * CC + gl * 16;
        float s = 0.0f;
#pragma unroll
        for (int j = 0; j < 4; ++j) {
            float4 ev = *(const float4*)(er + 4 * j);
            float4 dv = *(const float4*)&dec_s[gl * 16 + 4 * j];
            float4 vv = *(const float4*)&v_s[gl * 16 + 4 * j];
            s += fast_tanh(ev.x + dv.x) * vv.x;
            s += fast_tanh(ev.y + dv.y) * vv.y;
            s += fast_tanh(ev.z + dv.z) * vv.z;
            s += fast_tanh(ev.w + dv.w) * vv.w;
        }
        s += __shfl_xor(s, 1);
        s += __shfl_xor(s, 2);
        s += __shfl_xor(s, 4);
        s += __shfl_xor(s, 8);
        if (gl == 0) prod[e] = s;
    }
    __syncthreads();

    // log_softmax over the 512 prod values (each thread owns 2)
    float p0 = prod[tid], p1 = prod[tid + 256];
    float m = fmaxf(p0, p1);
#pragma unroll
    for (int off = 1; off < 64; off <<= 1) m = fmaxf(m, __shfl_xor(m, off));
    if (lane == 0) red[w] = m;
    __syncthreads();
    m = fmaxf(fmaxf(red[0], red[1]), fmaxf(red[2], red[3]));

    float s = __expf(p0 - m) + __expf(p1 - m);
#pragma unroll
    for (int off = 1; off < 64; off <<= 1) s += __shfl_xor(s, off);
    if (lane == 0) red[4 + w] = s;
    __syncthreads();
    s = red[4] + red[5] + red[6] + red[7];

    const float ls = m + __logf(s);
    float* o = out + bn * NE;
    o[tid]       = p0 - ls;
    o[tid + 256] = p1 - ls;
}

// ---------------------------------------------------------------------------
extern "C" void kernel_launch(void* const* d_in, const int* in_sizes, int n_in,
                              void* d_out, int out_size, void* d_ws, size_t ws_size,
                              hipStream_t stream) {
    const float* xdec = (const float*)d_in[0];   // (4,256,256)
    const float* xenc = (const float*)d_in[1];   // (4,512,256)
    const float* w1   = (const float*)d_in[2];   // (256,256)
    const float* w2   = (const float*)d_in[3];   // (256,256)
    const float* v    = (const float*)d_in[4];   // (1,256)
    float* out = (float*)d_out;                  // (4,256,512)

    float* enc_t = (float*)d_ws;                 // 2048*256 f32 = 2 MB
    float* dec_t = enc_t + BB * NE * CC;         // 1024*256 f32 = 1 MB

    dim3 gproj(48, 4);                           // 3072 rows / 64, 256 cols / 64
    proj_kernel<<<gproj, 256, 0, stream>>>(xdec, xenc, w1, w2, enc_t, dec_t);
    attn_kernel<<<BB * ND, 256, 0, stream>>>(enc_t, dec_t, v, out);
}

// Round 3
// 47.218 us; speedup vs baseline: 2.1591x; 2.1591x over previous
//
#include <hip/hip_runtime.h>
#include <math.h>

#define BB 4
#define ND 256
#define NE 512
#define CC 256

#define K2E 2.8853900817779268f   // 2 * log2(e): exp2(K2E*x) = e^{2x}
#define LOG2E 1.4426950408889634f
#define LN2 0.6931471805599453f

// ---------------------------------------------------------------------------
// Projection GEMM + exp epilogue.
//   rows 0..2047   : Eexp[b,e,c] = exp2(K2E * clamp(x_enc @ w1^T, +-13))
//   rows 2048..3071: Dexp[b,n,c] = exp2(K2E * clamp(x_dec @ w2^T, +-13))
// so that e^{2(enc+dec)} = Eexp * Dexp in the fused kernel.
// 64x64 tile per 256-thread block, K-step 16, fp32 vector FMA.
// ---------------------------------------------------------------------------
__global__ __launch_bounds__(256) void proj_kernel(
    const float* __restrict__ xdec, const float* __restrict__ xenc,
    const float* __restrict__ w1,   const float* __restrict__ w2,
    float* __restrict__ Eexp, float* __restrict__ Dexp)
{
    __shared__ float Xs[16][68];
    __shared__ float Ws[16][68];

    const int row0 = blockIdx.x * 64;
    const int col0 = blockIdx.y * 64;
    const bool is_enc = (row0 < BB * NE);

    const float* X = is_enc ? xenc : xdec;
    const float* W = is_enc ? w1   : w2;
    float*       Y = is_enc ? Eexp : Dexp;
    const int xrow0 = is_enc ? row0 : (row0 - BB * NE);

    const int tid = threadIdx.x;
    const int lr = tid >> 2;
    const int lk = (tid & 3) << 2;
    const int ty = tid >> 4;
    const int tx = tid & 15;

    float acc[4][4] = {};

    for (int k0 = 0; k0 < CC; k0 += 16) {
        float4 xv = *(const float4*)&X[(xrow0 + lr) * CC + k0 + lk];
        float4 wv = *(const float4*)&W[(col0  + lr) * CC + k0 + lk];
        __syncthreads();
        Xs[lk + 0][lr] = xv.x; Xs[lk + 1][lr] = xv.y;
        Xs[lk + 2][lr] = xv.z; Xs[lk + 3][lr] = xv.w;
        Ws[lk + 0][lr] = wv.x; Ws[lk + 1][lr] = wv.y;
        Ws[lk + 2][lr] = wv.z; Ws[lk + 3][lr] = wv.w;
        __syncthreads();
#pragma unroll
        for (int k = 0; k < 16; ++k) {
            float4 a = *(const float4*)&Xs[k][ty * 4];
            float4 b = *(const float4*)&Ws[k][tx * 4];
            acc[0][0] += a.x * b.x; acc[0][1] += a.x * b.y;
            acc[0][2] += a.x * b.z; acc[0][3] += a.x * b.w;
            acc[1][0] += a.y * b.x; acc[1][1] += a.y * b.y;
            acc[1][2] += a.y * b.z; acc[1][3] += a.y * b.w;
            acc[2][0] += a.z * b.x; acc[2][1] += a.z * b.y;
            acc[2][2] += a.z * b.z; acc[2][3] += a.z * b.w;
            acc[3][0] += a.w * b.x; acc[3][1] += a.w * b.y;
            acc[3][2] += a.w * b.z; acc[3][3] += a.w * b.w;
        }
    }

#pragma unroll
    for (int i = 0; i < 4; ++i) {
        float4 o;
        o.x = __builtin_amdgcn_exp2f(K2E * fminf(fmaxf(acc[i][0], -13.f), 13.f));
        o.y = __builtin_amdgcn_exp2f(K2E * fminf(fmaxf(acc[i][1], -13.f), 13.f));
        o.z = __builtin_amdgcn_exp2f(K2E * fminf(fmaxf(acc[i][2], -13.f), 13.f));
        o.w = __builtin_amdgcn_exp2f(K2E * fminf(fmaxf(acc[i][3], -13.f), 13.f));
        *(float4*)&Y[(xrow0 + ty * 4 + i) * CC + col0 + tx * 4] = o;
    }
}

// ---------------------------------------------------------------------------
// Fused tanh-dot + log_softmax, factored form:
//   tanh(e+d) = 1 - 2/(1 + Eexp*Dexp)
//   prod[b,n,e] = V - 2 * sum_c v_c / (1 + Eexp[b,e,c]*Dexp[b,n,c]),  V = sum_c v_c
// One 512-thread block per (b, 4 decoder rows); grid = BB*ND/4 = 256 blocks.
// 32 subgroups of 16 lanes; each subgroup owns one e, lane covers 16 c in
// registers (v, dec, enc all register-resident in the hot loop -> zero LDS
// traffic, 2 VALU + 1 rcp per element). Then 4 wave-level log_softmaxes.
// ---------------------------------------------------------------------------
__global__ __launch_bounds__(512) void attn_kernel(
    const float* __restrict__ Eexp, const float* __restrict__ Dexp,
    const float* __restrict__ v, float* __restrict__ out)
{
    __shared__ float prod[4][NE];   // 8 KB

    const int blk = blockIdx.x;       // 0..255
    const int b   = blk >> 6;
    const int n0  = (blk & 63) * 4;
    const int tid  = threadIdx.x;
    const int w    = tid >> 6;        // wave 0..7
    const int lane = tid & 63;
    const int gl   = tid & 15;        // lane in 16-lane subgroup
    const int sg   = tid >> 4;        // subgroup 0..31
    const int c0   = gl * 16;

    // v slice in registers + block-wide constant V = sum_c v_c
    float vv[16];
    float vs = 0.0f;
#pragma unroll
    for (int j = 0; j < 16; j += 4) {
        float4 t = *(const float4*)&v[c0 + j];
        vv[j] = t.x; vv[j+1] = t.y; vv[j+2] = t.z; vv[j+3] = t.w;
        vs += t.x + t.y + t.z + t.w;
    }
    vs += __shfl_xor(vs, 1); vs += __shfl_xor(vs, 2);
    vs += __shfl_xor(vs, 4); vs += __shfl_xor(vs, 8);
    const float V = vs;

    // Dexp slices for the 4 decoder rows, in registers
    float dd[4][16];
#pragma unroll
    for (int n = 0; n < 4; ++n) {
        const float* dp = Dexp + (size_t)(b * ND + n0 + n) * CC + c0;
#pragma unroll
        for (int j = 0; j < 16; j += 4) {
            float4 t = *(const float4*)(dp + j);
            dd[n][j] = t.x; dd[n][j+1] = t.y; dd[n][j+2] = t.z; dd[n][j+3] = t.w;
        }
    }

    const float* Eb = Eexp + (size_t)b * NE * CC;

#define LOADE(dst, EIDX) do {                                   \
        const float* _p = Eb + (size_t)(EIDX) * CC + c0;        \
        float4 _q0 = *(const float4*)(_p);                      \
        float4 _q1 = *(const float4*)(_p + 4);                  \
        float4 _q2 = *(const float4*)(_p + 8);                  \
        float4 _q3 = *(const float4*)(_p + 12);                 \
        dst[0]=_q0.x; dst[1]=_q0.y; dst[2]=_q0.z; dst[3]=_q0.w; \
        dst[4]=_q1.x; dst[5]=_q1.y; dst[6]=_q1.z; dst[7]=_q1.w; \
        dst[8]=_q2.x; dst[9]=_q2.y; dst[10]=_q2.z; dst[11]=_q2.w; \
        dst[12]=_q3.x; dst[13]=_q3.y; dst[14]=_q3.z; dst[15]=_q3.w; \
    } while (0)

    float cur[16], nxt[16];
    LOADE(cur, sg);

    for (int e0 = 0; e0 < NE; e0 += 32) {
        const int e = e0 + sg;
        if (e0 + 32 < NE) LOADE(nxt, e0 + 32 + sg);

        float a0 = 0.f, a1 = 0.f, a2 = 0.f, a3 = 0.f;
#pragma unroll
        for (int j = 0; j < 16; ++j) {
            const float E = cur[j];
            const float r0 = __builtin_amdgcn_rcpf(fmaf(E, dd[0][j], 1.0f));
            const float r1 = __builtin_amdgcn_rcpf(fmaf(E, dd[1][j], 1.0f));
            const float r2 = __builtin_amdgcn_rcpf(fmaf(E, dd[2][j], 1.0f));
            const float r3 = __builtin_amdgcn_rcpf(fmaf(E, dd[3][j], 1.0f));
            a0 = fmaf(vv[j], r0, a0);
            a1 = fmaf(vv[j], r1, a1);
            a2 = fmaf(vv[j], r2, a2);
            a3 = fmaf(vv[j], r3, a3);
        }
#pragma unroll
        for (int off = 1; off < 16; off <<= 1) {
            a0 += __shfl_xor(a0, off);
            a1 += __shfl_xor(a1, off);
            a2 += __shfl_xor(a2, off);
            a3 += __shfl_xor(a3, off);
        }
        if (gl == 0) {
            prod[0][e] = V - 2.0f * a0;
            prod[1][e] = V - 2.0f * a1;
            prod[2][e] = V - 2.0f * a2;
            prod[3][e] = V - 2.0f * a3;
        }
#pragma unroll
        for (int j = 0; j < 16; ++j) cur[j] = nxt[j];
    }
#undef LOADE

    __syncthreads();

    // log_softmax: wave w (w<4) handles decoder row n0+w; 8 values/lane,
    // stride-64 (2-way bank alias only).
    if (w < 4) {
        float p[8];
#pragma unroll
        for (int i = 0; i < 8; ++i) p[i] = prod[w][lane + 64 * i];
        float m = p[0];
#pragma unroll
        for (int i = 1; i < 8; ++i) m = fmaxf(m, p[i]);
#pragma unroll
        for (int off = 1; off < 64; off <<= 1) m = fmaxf(m, __shfl_xor(m, off));
        float s = 0.f;
#pragma unroll
        for (int i = 0; i < 8; ++i) s += __builtin_amdgcn_exp2f((p[i] - m) * LOG2E);
#pragma unroll
        for (int off = 1; off < 64; off <<= 1) s += __shfl_xor(s, off);
        const float lse = m + __builtin_amdgcn_logf(s) * LN2;

        float* o = out + (size_t)(b * ND + n0 + w) * NE;
#pragma unroll
        for (int i = 0; i < 8; ++i) o[lane + 64 * i] = p[i] - lse;
    }
}

// ---------------------------------------------------------------------------
extern "C" void kernel_launch(void* const* d_in, const int* in_sizes, int n_in,
                              void* d_out, int out_size, void* d_ws, size_t ws_size,
                              hipStream_t stream) {
    const float* xdec = (const float*)d_in[0];   // (4,256,256)
    const float* xenc = (const float*)d_in[1];   // (4,512,256)
    const float* w1   = (const float*)d_in[2];   // (256,256)
    const float* w2   = (const float*)d_in[3];   // (256,256)
    const float* v    = (const float*)d_in[4];   // (1,256)
    float* out = (float*)d_out;                  // (4,256,512)

    float* Eexp = (float*)d_ws;                  // 2048*256 f32 = 2 MB
    float* Dexp = Eexp + BB * NE * CC;           // 1024*256 f32 = 1 MB

    dim3 gproj(48, 4);
    proj_kernel<<<gproj, 256, 0, stream>>>(xdec, xenc, w1, w2, Eexp, Dexp);
    attn_kernel<<<(BB * ND) / 4, 512, 0, stream>>>(Eexp, Dexp, v, out);
}

// Round 4
// 40.975 us; speedup vs baseline: 2.4880x; 1.1523x over previous
//
#include <hip/hip_runtime.h>
#include <math.h>

#define BB 4
#define ND 256
#define NE 512
#define CC 256

#define K2E 2.8853900817779268f   // 2 * log2(e): exp2(K2E*x) = e^{2x}
#define LOG2E 1.4426950408889634f
#define LN2 0.6931471805599453f

// ---------------------------------------------------------------------------
// Projection GEMM + exp epilogue.
//   enc rows (0..2047):   Et[b][c][e] = exp2(K2E*clamp(x_enc@w1^T, +-13))  TRANSPOSED
//   dec rows (2048..3071): Dexp[n][c] = exp2(K2E*clamp(x_dec@w2^T, +-13))  row-major
// 32(rows) x 64(cols) tile per 256-thread block; grid (96,4) = 384 blocks.
// ---------------------------------------------------------------------------
__global__ __launch_bounds__(256) void proj_kernel(
    const float* __restrict__ xdec, const float* __restrict__ xenc,
    const float* __restrict__ w1,   const float* __restrict__ w2,
    float* __restrict__ Et, float* __restrict__ Dexp)
{
    __shared__ float Xs[16][36];   // [k][row], stride 36 -> float4-aligned rows
    __shared__ float Ws[16][68];   // [k][col], stride 68 -> float2-aligned rows

    const int row0 = blockIdx.x * 32;
    const int col0 = blockIdx.y * 64;
    const bool is_enc = (row0 < BB * NE);

    const float* X = is_enc ? xenc : xdec;
    const float* W = is_enc ? w1   : w2;
    const int xrow0 = is_enc ? row0 : (row0 - BB * NE);

    const int tid = threadIdx.x;
    const int xr = tid >> 3, xk = (tid & 7) * 2;   // X loader: float2
    const int wc = tid >> 2, wk = (tid & 3) * 4;   // W loader: float4
    const int ty = tid >> 5;                        // 0..7 (4 rows each)
    const int tx = tid & 31;                        // 0..31 (2 cols each)

    float acc[4][2] = {};

    for (int k0 = 0; k0 < CC; k0 += 16) {
        float2 xv = *(const float2*)&X[(xrow0 + xr) * CC + k0 + xk];
        float4 wv = *(const float4*)&W[(col0 + wc) * CC + k0 + wk];
        __syncthreads();
        Xs[xk][xr] = xv.x; Xs[xk + 1][xr] = xv.y;
        Ws[wk][wc] = wv.x; Ws[wk + 1][wc] = wv.y;
        Ws[wk + 2][wc] = wv.z; Ws[wk + 3][wc] = wv.w;
        __syncthreads();
#pragma unroll
        for (int k = 0; k < 16; ++k) {
            float4 a = *(const float4*)&Xs[k][ty * 4];   // broadcast within half-wave
            float2 b = *(const float2*)&Ws[k][tx * 2];   // 2-way alias (free)
            acc[0][0] += a.x * b.x; acc[0][1] += a.x * b.y;
            acc[1][0] += a.y * b.x; acc[1][1] += a.y * b.y;
            acc[2][0] += a.z * b.x; acc[2][1] += a.z * b.y;
            acc[3][0] += a.w * b.x; acc[3][1] += a.w * b.y;
        }
    }

    float ex[4][2];
#pragma unroll
    for (int i = 0; i < 4; ++i)
#pragma unroll
        for (int j = 0; j < 2; ++j)
            ex[i][j] = __builtin_amdgcn_exp2f(
                K2E * fminf(fmaxf(acc[i][j], -13.f), 13.f));

    if (is_enc) {
        const int b  = row0 >> 9;                 // 512 enc rows per batch
        const int e0 = (row0 & 511) + ty * 4;
#pragma unroll
        for (int j = 0; j < 2; ++j) {
            float4 o = make_float4(ex[0][j], ex[1][j], ex[2][j], ex[3][j]);
            *(float4*)&Et[((size_t)b * CC + col0 + tx * 2 + j) * NE + e0] = o;
        }
    } else {
#pragma unroll
        for (int i = 0; i < 4; ++i) {
            float2 o = make_float2(ex[i][0], ex[i][1]);
            *(float2*)&Dexp[(size_t)(xrow0 + ty * 4 + i) * CC + col0 + tx * 2] = o;
        }
    }
}

// ---------------------------------------------------------------------------
// Fused tanh-dot + log_softmax, lane-per-e form (no shuffles in hot loop):
//   p'[n,e] = -2 * sum_c v_c / (1 + Et[b][c][e]*Dexp[n][c])
// (the +sum(v) shift cancels in log_softmax). One 512-thread block per
// (b, 4 decoder rows); tid == e; E loads coalesced; v/D broadcast from LDS;
// per element exactly fma+rcp+fma with 4 independent acc chains.
// ---------------------------------------------------------------------------
__global__ __launch_bounds__(512) void attn_kernel(
    const float* __restrict__ Et, const float* __restrict__ Dexp,
    const float* __restrict__ v, float* __restrict__ out)
{
    __shared__ float v_s[CC];
    __shared__ float D_s[4][CC];
    __shared__ float prod[4][NE];

    const int blk = blockIdx.x;       // 0..255
    const int b   = blk >> 6;
    const int n0  = (blk & 63) * 4;
    const int tid = threadIdx.x;      // == e, 0..511

    if (tid < CC) v_s[tid] = v[tid];
    for (int i = tid; i < 4 * CC; i += 512)
        D_s[i >> 8][i & 255] = Dexp[(size_t)(b * ND + n0 + (i >> 8)) * CC + (i & 255)];
    __syncthreads();

    const float* Ecol = Et + (size_t)b * CC * NE + tid;

    float a0 = 0.f, a1 = 0.f, a2 = 0.f, a3 = 0.f;
    float Ev0[16], Ev1[16];

#define PROC1(EV, VQ, D0, D1, D2, D3) do {                                   \
        const float _E = (EV);                                               \
        a0 = fmaf((VQ), __builtin_amdgcn_rcpf(fmaf(_E, (D0), 1.0f)), a0);    \
        a1 = fmaf((VQ), __builtin_amdgcn_rcpf(fmaf(_E, (D1), 1.0f)), a1);    \
        a2 = fmaf((VQ), __builtin_amdgcn_rcpf(fmaf(_E, (D2), 1.0f)), a2);    \
        a3 = fmaf((VQ), __builtin_amdgcn_rcpf(fmaf(_E, (D3), 1.0f)), a3);    \
    } while (0)

#define PROCESS(EV, CB) do {                                                 \
        _Pragma("unroll")                                                    \
        for (int cs = 0; cs < 16; cs += 4) {                                 \
            float4 vq = *(const float4*)&v_s[(CB) + cs];                     \
            float4 q0 = *(const float4*)&D_s[0][(CB) + cs];                  \
            float4 q1 = *(const float4*)&D_s[1][(CB) + cs];                  \
            float4 q2 = *(const float4*)&D_s[2][(CB) + cs];                  \
            float4 q3 = *(const float4*)&D_s[3][(CB) + cs];                  \
            PROC1(EV[cs + 0], vq.x, q0.x, q1.x, q2.x, q3.x);                 \
            PROC1(EV[cs + 1], vq.y, q0.y, q1.y, q2.y, q3.y);                 \
            PROC1(EV[cs + 2], vq.z, q0.z, q1.z, q2.z, q3.z);                 \
            PROC1(EV[cs + 3], vq.w, q0.w, q1.w, q2.w, q3.w);                 \
        }                                                                    \
    } while (0)

#pragma unroll
    for (int j = 0; j < 16; ++j) Ev0[j] = Ecol[(size_t)j * NE];

    for (int c0 = 0; c0 < CC; c0 += 32) {
#pragma unroll
        for (int j = 0; j < 16; ++j) Ev1[j] = Ecol[(size_t)(c0 + 16 + j) * NE];
        PROCESS(Ev0, c0);
        if (c0 + 32 < CC) {
#pragma unroll
            for (int j = 0; j < 16; ++j) Ev0[j] = Ecol[(size_t)(c0 + 32 + j) * NE];
        }
        PROCESS(Ev1, c0 + 16);
    }
#undef PROCESS
#undef PROC1

    prod[0][tid] = -2.0f * a0;
    prod[1][tid] = -2.0f * a1;
    prod[2][tid] = -2.0f * a2;
    prod[3][tid] = -2.0f * a3;
    __syncthreads();

    // log_softmax: wave w (w<4) handles decoder row n0+w
    const int w    = tid >> 6;
    const int lane = tid & 63;
    if (w < 4) {
        float p[8];
#pragma unroll
        for (int i = 0; i < 8; ++i) p[i] = prod[w][lane + 64 * i];
        float m = p[0];
#pragma unroll
        for (int i = 1; i < 8; ++i) m = fmaxf(m, p[i]);
#pragma unroll
        for (int off = 1; off < 64; off <<= 1) m = fmaxf(m, __shfl_xor(m, off));
        float s = 0.f;
#pragma unroll
        for (int i = 0; i < 8; ++i) s += __builtin_amdgcn_exp2f((p[i] - m) * LOG2E);
#pragma unroll
        for (int off = 1; off < 64; off <<= 1) s += __shfl_xor(s, off);
        const float lse = m + __builtin_amdgcn_logf(s) * LN2;

        float* o = out + (size_t)(b * ND + n0 + w) * NE;
#pragma unroll
        for (int i = 0; i < 8; ++i) o[lane + 64 * i] = p[i] - lse;
    }
}

// ---------------------------------------------------------------------------
extern "C" void kernel_launch(void* const* d_in, const int* in_sizes, int n_in,
                              void* d_out, int out_size, void* d_ws, size_t ws_size,
                              hipStream_t stream) {
    const float* xdec = (const float*)d_in[0];   // (4,256,256)
    const float* xenc = (const float*)d_in[1];   // (4,512,256)
    const float* w1   = (const float*)d_in[2];   // (256,256)
    const float* w2   = (const float*)d_in[3];   // (256,256)
    const float* v    = (const float*)d_in[4];   // (1,256)
    float* out = (float*)d_out;                  // (4,256,512)

    float* Et   = (float*)d_ws;                  // [4][256][512] f32 = 2 MB (transposed)
    float* Dexp = Et + (size_t)BB * CC * NE;     // [1024][256] f32 = 1 MB

    dim3 gproj(96, 4);                           // 3072 rows / 32, 256 cols / 64
    proj_kernel<<<gproj, 256, 0, stream>>>(xdec, xenc, w1, w2, Et, Dexp);
    attn_kernel<<<(BB * ND) / 4, 512, 0, stream>>>(Et, Dexp, v, out);
}

// Round 5
// 40.385 us; speedup vs baseline: 2.5244x; 1.0146x over previous
//
#include <hip/hip_runtime.h>
#include <math.h>

#define BB 4
#define ND 256
#define NE 512
#define CC 256

#define K2E 2.8853900817779268f   // 2 * log2(e): exp2(K2E*x) = e^{2x}
#define LOG2E 1.4426950408889634f
#define LN2 0.6931471805599453f

// ---------------------------------------------------------------------------
// Projection GEMM + exp epilogue (unchanged from R4).
//   enc rows:  Et[b][c][e] = exp2(K2E*clamp(x_enc@w1^T, +-13))  TRANSPOSED
//   dec rows:  Dexp[n][c]  = exp2(K2E*clamp(x_dec@w2^T, +-13))  row-major
// ---------------------------------------------------------------------------
__global__ __launch_bounds__(256) void proj_kernel(
    const float* __restrict__ xdec, const float* __restrict__ xenc,
    const float* __restrict__ w1,   const float* __restrict__ w2,
    float* __restrict__ Et, float* __restrict__ Dexp)
{
    __shared__ float Xs[16][36];
    __shared__ float Ws[16][68];

    const int row0 = blockIdx.x * 32;
    const int col0 = blockIdx.y * 64;
    const bool is_enc = (row0 < BB * NE);

    const float* X = is_enc ? xenc : xdec;
    const float* W = is_enc ? w1   : w2;
    const int xrow0 = is_enc ? row0 : (row0 - BB * NE);

    const int tid = threadIdx.x;
    const int xr = tid >> 3, xk = (tid & 7) * 2;
    const int wc = tid >> 2, wk = (tid & 3) * 4;
    const int ty = tid >> 5;
    const int tx = tid & 31;

    float acc[4][2] = {};

    for (int k0 = 0; k0 < CC; k0 += 16) {
        float2 xv = *(const float2*)&X[(xrow0 + xr) * CC + k0 + xk];
        float4 wv = *(const float4*)&W[(col0 + wc) * CC + k0 + wk];
        __syncthreads();
        Xs[xk][xr] = xv.x; Xs[xk + 1][xr] = xv.y;
        Ws[wk][wc] = wv.x; Ws[wk + 1][wc] = wv.y;
        Ws[wk + 2][wc] = wv.z; Ws[wk + 3][wc] = wv.w;
        __syncthreads();
#pragma unroll
        for (int k = 0; k < 16; ++k) {
            float4 a = *(const float4*)&Xs[k][ty * 4];
            float2 b = *(const float2*)&Ws[k][tx * 2];
            acc[0][0] += a.x * b.x; acc[0][1] += a.x * b.y;
            acc[1][0] += a.y * b.x; acc[1][1] += a.y * b.y;
            acc[2][0] += a.z * b.x; acc[2][1] += a.z * b.y;
            acc[3][0] += a.w * b.x; acc[3][1] += a.w * b.y;
        }
    }

    float ex[4][2];
#pragma unroll
    for (int i = 0; i < 4; ++i)
#pragma unroll
        for (int j = 0; j < 2; ++j)
            ex[i][j] = __builtin_amdgcn_exp2f(
                K2E * fminf(fmaxf(acc[i][j], -13.f), 13.f));

    if (is_enc) {
        const int b  = row0 >> 9;
        const int e0 = (row0 & 511) + ty * 4;
#pragma unroll
        for (int j = 0; j < 2; ++j) {
            float4 o = make_float4(ex[0][j], ex[1][j], ex[2][j], ex[3][j]);
            *(float4*)&Et[((size_t)b * CC + col0 + tx * 2 + j) * NE + e0] = o;
        }
    } else {
#pragma unroll
        for (int i = 0; i < 4; ++i) {
            float2 o = make_float2(ex[i][0], ex[i][1]);
            *(float2*)&Dexp[(size_t)(xrow0 + ty * 4 + i) * CC + col0 + tx * 2] = o;
        }
    }
}

// ---------------------------------------------------------------------------
// Fused tanh-dot + log_softmax, PAIRED-division form:
//   v0/d0 + v1/d1 = (v0*d1 + v1*d0) / (d0*d1),  d = fma(E, D, 1)
// -> 1 rcp + 6 VALU per 2 elements (was 2 rcp + 4 VALU).
// One 512-thread block per (b, 4 decoder rows); tid == e.
// ---------------------------------------------------------------------------
__global__ __launch_bounds__(512) void attn_kernel(
    const float* __restrict__ Et, const float* __restrict__ Dexp,
    const float* __restrict__ v, float* __restrict__ out)
{
    __shared__ float v_s[CC];
    __shared__ float D_s[4][CC];
    __shared__ float prod[4][NE];

    const int blk = blockIdx.x;       // 0..255
    const int b   = blk >> 6;
    const int n0  = (blk & 63) * 4;
    const int tid = threadIdx.x;      // == e, 0..511

    if (tid < CC) v_s[tid] = v[tid];
    for (int i = tid; i < 4 * CC; i += 512)
        D_s[i >> 8][i & 255] = Dexp[(size_t)(b * ND + n0 + (i >> 8)) * CC + (i & 255)];
    __syncthreads();

    const float* Ecol = Et + (size_t)b * CC * NE + tid;

    float a0 = 0.f, a1 = 0.f, a2 = 0.f, a3 = 0.f;
    float Ev0[16], Ev1[16];

// one paired step: elements (c,c+1) for one accumulator row
//   d0=fma(E0,D0,1); d1=fma(E1,D1,1); acc = fma(v0*d1 + v1*d0, rcp(d0*d1), acc)
#define PAIR(ACC, E0, E1, V0, V1, D0, D1) do {                               \
        const float _d0 = fmaf((E0), (D0), 1.0f);                            \
        const float _d1 = fmaf((E1), (D1), 1.0f);                            \
        const float _num = fmaf((V1), _d0, (V0) * _d1);                      \
        ACC = fmaf(_num, __builtin_amdgcn_rcpf(_d0 * _d1), ACC);             \
    } while (0)

#define PROCESS(EV, CB) do {                                                 \
        _Pragma("unroll")                                                    \
        for (int cs = 0; cs < 16; cs += 4) {                                 \
            float4 vq = *(const float4*)&v_s[(CB) + cs];                     \
            float4 q0 = *(const float4*)&D_s[0][(CB) + cs];                  \
            float4 q1 = *(const float4*)&D_s[1][(CB) + cs];                  \
            float4 q2 = *(const float4*)&D_s[2][(CB) + cs];                  \
            float4 q3 = *(const float4*)&D_s[3][(CB) + cs];                  \
            PAIR(a0, EV[cs + 0], EV[cs + 1], vq.x, vq.y, q0.x, q0.y);        \
            PAIR(a1, EV[cs + 0], EV[cs + 1], vq.x, vq.y, q1.x, q1.y);        \
            PAIR(a2, EV[cs + 0], EV[cs + 1], vq.x, vq.y, q2.x, q2.y);        \
            PAIR(a3, EV[cs + 0], EV[cs + 1], vq.x, vq.y, q3.x, q3.y);        \
            PAIR(a0, EV[cs + 2], EV[cs + 3], vq.z, vq.w, q0.z, q0.w);        \
            PAIR(a1, EV[cs + 2], EV[cs + 3], vq.z, vq.w, q1.z, q1.w);        \
            PAIR(a2, EV[cs + 2], EV[cs + 3], vq.z, vq.w, q2.z, q2.w);        \
            PAIR(a3, EV[cs + 2], EV[cs + 3], vq.z, vq.w, q3.z, q3.w);        \
        }                                                                    \
    } while (0)

#pragma unroll
    for (int j = 0; j < 16; ++j) Ev0[j] = Ecol[(size_t)j * NE];

    for (int c0 = 0; c0 < CC; c0 += 32) {
#pragma unroll
        for (int j = 0; j < 16; ++j) Ev1[j] = Ecol[(size_t)(c0 + 16 + j) * NE];
        PROCESS(Ev0, c0);
        if (c0 + 32 < CC) {
#pragma unroll
            for (int j = 0; j < 16; ++j) Ev0[j] = Ecol[(size_t)(c0 + 32 + j) * NE];
        }
        PROCESS(Ev1, c0 + 16);
    }
#undef PROCESS
#undef PAIR

    prod[0][tid] = -2.0f * a0;
    prod[1][tid] = -2.0f * a1;
    prod[2][tid] = -2.0f * a2;
    prod[3][tid] = -2.0f * a3;
    __syncthreads();

    // log_softmax: wave w (w<4) handles decoder row n0+w
    const int w    = tid >> 6;
    const int lane = tid & 63;
    if (w < 4) {
        float p[8];
#pragma unroll
        for (int i = 0; i < 8; ++i) p[i] = prod[w][lane + 64 * i];
        float m = p[0];
#pragma unroll
        for (int i = 1; i < 8; ++i) m = fmaxf(m, p[i]);
#pragma unroll
        for (int off = 1; off < 64; off <<= 1) m = fmaxf(m, __shfl_xor(m, off));
        float s = 0.f;
#pragma unroll
        for (int i = 0; i < 8; ++i) s += __builtin_amdgcn_exp2f((p[i] - m) * LOG2E);
#pragma unroll
        for (int off = 1; off < 64; off <<= 1) s += __shfl_xor(s, off);
        const float lse = m + __builtin_amdgcn_logf(s) * LN2;

        float* o = out + (size_t)(b * ND + n0 + w) * NE;
#pragma unroll
        for (int i = 0; i < 8; ++i) o[lane + 64 * i] = p[i] - lse;
    }
}

// ---------------------------------------------------------------------------
extern "C" void kernel_launch(void* const* d_in, const int* in_sizes, int n_in,
                              void* d_out, int out_size, void* d_ws, size_t ws_size,
                              hipStream_t stream) {
    const float* xdec = (const float*)d_in[0];   // (4,256,256)
    const float* xenc = (const float*)d_in[1];   // (4,512,256)
    const float* w1   = (const float*)d_in[2];   // (256,256)
    const float* w2   = (const float*)d_in[3];   // (256,256)
    const float* v    = (const float*)d_in[4];   // (1,256)
    float* out = (float*)d_out;                  // (4,256,512)

    float* Et   = (float*)d_ws;                  // [4][256][512] f32 = 2 MB (transposed)
    float* Dexp = Et + (size_t)BB * CC * NE;     // [1024][256] f32 = 1 MB

    dim3 gproj(96, 4);
    proj_kernel<<<gproj, 256, 0, stream>>>(xdec, xenc, w1, w2, Et, Dexp);
    attn_kernel<<<(BB * ND) / 4, 512, 0, stream>>>(Et, Dexp, v, out);
}